// Round 1
// baseline (279.307 us; speedup 1.0000x reference)
//
#include <hip/hip_runtime.h>
#include <hip/hip_bf16.h>

// FlowNetC correlation: B=4, C=256, H=W=96, PAD=MAX_DISP=20, STRIDE2=2, D=21.
// out[b, oy*21+ox, h, w] = (1/C) * sum_c x1[b,c,h,w] * x2[b,c,h+2oy-20,w+2ox-20]
// (zero outside bounds).
//
// Strategy: dx always even -> split w by parity. Per (b,h,dy,par):
//   out[i,e] = sum_c A[c,i] * B[c,i+e-10],  i in [0,48), e in [0,21)
// Band GEMM with bf16 MFMA 16x16x32: M-tiles i0 in {0,16,32}; padded j axis
// jpad = j+16 in [0,80) so each M-tile needs exactly N-tiles jpad0 = i0+16t,
// t in {0,1,2}. ox = 16t + n - m - 6.

typedef __bf16 bf16x8 __attribute__((ext_vector_type(8)));
typedef float f32x4 __attribute__((ext_vector_type(4)));

#define B_ 4
#define C_ 256
#define H_ 96
#define W_ 96
#define NOFF 21
#define IHALF 48
#define JPAD 80
#define JOFF 16

#define X1T_ELEMS (B_ * H_ * 2 * IHALF * C_)   // 9,437,184 ushorts
#define X2T_ELEMS (B_ * H_ * 2 * JPAD * C_)    // 15,728,640 ushorts

__device__ __forceinline__ unsigned short f32_to_bf16_rne(float f) {
    union { float f; unsigned u; } v; v.f = f;
    unsigned u = v.u;
    return (unsigned short)((u + 0x7fffu + ((u >> 16) & 1u)) >> 16);
}

// ---------------------------------------------------------------------------
// Prep: fp32 NCHW -> bf16 transposed layouts in ws.
//   X1T [b][h][par][i][c]      (i = w>>1, par = w&1)
//   X2T [b][h][par][jpad][c]   (jpad = (w>>1)+16; rows 0..15 and 64..79 zero)
// ---------------------------------------------------------------------------
__global__ __launch_bounds__(256) void prep_kernel(const float* __restrict__ x1,
                                                   const float* __restrict__ x2,
                                                   unsigned short* __restrict__ ws) {
    __shared__ unsigned short lds[64][97];
    int bid = blockIdx.x;
    int which = (bid >= 1536) ? 1 : 0;
    if (which) bid -= 1536;
    int ct = bid & 3;
    int h  = (bid >> 2) % H_;
    int b  = bid / (4 * H_);
    int c0 = ct * 64;
    const float* src = which ? x2 : x1;
    const float* base = src + ((size_t)(b * C_ + c0) * H_ + h) * W_;

    for (int idx = threadIdx.x; idx < 64 * 96; idx += 256) {
        int c = idx / 96, w = idx % 96;
        lds[c][w] = f32_to_bf16_rne(base[c * (H_ * W_) + w]);
    }
    __syncthreads();

    if (!which) {
        for (int idx = threadIdx.x; idx < 96 * 64; idx += 256) {
            int cc = idx & 63, wi = idx >> 6;
            int par = wi & 1, i = wi >> 1;
            ws[((((b * H_ + h) * 2 + par) * IHALF + i) << 8) + c0 + cc] = lds[cc][wi];
        }
    } else {
        unsigned short* w2 = ws + X1T_ELEMS;
        for (int idx = threadIdx.x; idx < 96 * 64; idx += 256) {
            int cc = idx & 63, wi = idx >> 6;
            int par = wi & 1, jp = (wi >> 1) + JOFF;
            w2[((((b * H_ + h) * 2 + par) * JPAD + jp) << 8) + c0 + cc] = lds[cc][wi];
        }
        // zero the pad rows (jpad 0..15 and 64..79) for this c-slice
        for (int idx = threadIdx.x; idx < 64 * 64; idx += 256) {
            int cc = idx & 63, pr = idx >> 6;       // pr in [0,64)
            int par = pr >> 5, rr = pr & 31;
            int jp = (rr < 16) ? rr : (rr + 48);    // 0..15 or 64..79
            w2[((((b * H_ + h) * 2 + par) * JPAD + jp) << 8) + c0 + cc] = 0;
        }
    }
}

// ---------------------------------------------------------------------------
// Main: one block per (b, h, oy). 6 waves = (par in {0,1}) x (M-tile in {0,1,2}).
// ---------------------------------------------------------------------------
__global__ __launch_bounds__(384) void corr_kernel(const unsigned short* __restrict__ ws,
                                                   float* __restrict__ out) {
    __shared__ float sl[NOFF][97];
    int bid = blockIdx.x;
    int oy = bid % NOFF;
    int h  = (bid / NOFF) % H_;
    int b  = bid / (NOFF * H_);
    int dy = 2 * oy - 20;
    int h2 = h + dy;
    int tid = threadIdx.x;
    int outbase = ((b * 441 + oy * NOFF) * H_ + h) * W_;   // + ox*9216 + w

    if (h2 < 0 || h2 >= H_) {
        for (int idx = tid; idx < NOFF * W_; idx += 384)
            out[outbase + (idx / W_) * (H_ * W_) + (idx % W_)] = 0.0f;
        return;
    }

    int wv   = tid >> 6;       // 0..5
    int lane = tid & 63;
    int par  = wv & 1;
    int mt   = wv >> 1;        // 0..2
    int i0   = mt * 16;

    const unsigned short* Abase = ws + ((((b * H_ + h)  * 2 + par) * IHALF) << 8);
    const unsigned short* Bbase = ws + X1T_ELEMS + ((((b * H_ + h2) * 2 + par) * JPAD) << 8);

    int mrow = lane & 15;
    int kq   = (lane >> 4) * 8;
    const unsigned short* aptr = Abase + ((i0 + mrow) << 8) + kq;
    const unsigned short* bptr = Bbase + ((i0 + mrow) << 8) + kq;  // t=0 tile: jpad0=i0

    f32x4 acc0 = {0.f, 0.f, 0.f, 0.f};
    f32x4 acc1 = {0.f, 0.f, 0.f, 0.f};
    f32x4 acc2 = {0.f, 0.f, 0.f, 0.f};

#pragma unroll
    for (int k0 = 0; k0 < C_; k0 += 32) {
        bf16x8 a  = *(const bf16x8*)(aptr + k0);
        bf16x8 b0 = *(const bf16x8*)(bptr + k0);
        bf16x8 b1 = *(const bf16x8*)(bptr + 16 * C_ + k0);
        bf16x8 b2 = *(const bf16x8*)(bptr + 32 * C_ + k0);
        acc0 = __builtin_amdgcn_mfma_f32_16x16x32_bf16(a, b0, acc0, 0, 0, 0);
        acc1 = __builtin_amdgcn_mfma_f32_16x16x32_bf16(a, b1, acc1, 0, 0, 0);
        acc2 = __builtin_amdgcn_mfma_f32_16x16x32_bf16(a, b2, acc2, 0, 0, 0);
    }

    // Epilogue: scatter valid band entries into LDS slab.
    // C/D layout: n(col)=lane&15, m(row)=(lane>>4)*4+reg  [verified m89/m91]
    int n = lane & 15;
    int quad = lane >> 4;
#pragma unroll
    for (int r = 0; r < 4; ++r) {
        int m = quad * 4 + r;
        int w = 2 * (i0 + m) + par;
        int ox0 = 0 * 16 + n - m - 6;
        int ox1 = 1 * 16 + n - m - 6;
        int ox2 = 2 * 16 + n - m - 6;
        if (ox0 >= 0 && ox0 < NOFF) sl[ox0][w] = acc0[r];
        if (ox1 >= 0 && ox1 < NOFF) sl[ox1][w] = acc1[r];
        if (ox2 >= 0 && ox2 < NOFF) sl[ox2][w] = acc2[r];
    }
    __syncthreads();

    for (int idx = tid; idx < NOFF * W_; idx += 384) {
        int ox = idx / W_, w = idx % W_;
        out[outbase + ox * (H_ * W_) + w] = sl[ox][w] * (1.0f / 256.0f);
    }
}

// ---------------------------------------------------------------------------
// Fallback (only if ws too small): direct fp32, slow but correct.
// ---------------------------------------------------------------------------
__global__ __launch_bounds__(256) void corr_fallback(const float* __restrict__ x1,
                                                     const float* __restrict__ x2,
                                                     float* __restrict__ out) {
    int bid = blockIdx.x;
    int oy = bid % NOFF, h = (bid / NOFF) % H_, b = bid / (NOFF * H_);
    int dy = 2 * oy - 20, h2 = h + dy;
    int outbase = ((b * 441 + oy * NOFF) * H_ + h) * W_;
    for (int idx = threadIdx.x; idx < NOFF * W_; idx += 256) {
        int ox = idx / W_, w = idx % W_;
        float acc = 0.f;
        int w2 = w + 2 * ox - 20;
        if (h2 >= 0 && h2 < H_ && w2 >= 0 && w2 < W_) {
            const float* p1 = x1 + (size_t)b * C_ * H_ * W_ + h * W_ + w;
            const float* p2 = x2 + (size_t)b * C_ * H_ * W_ + h2 * W_ + w2;
            for (int c = 0; c < C_; ++c) acc += p1[c * (H_ * W_)] * p2[c * (H_ * W_)];
        }
        out[outbase + ox * (H_ * W_) + w] = acc * (1.0f / 256.0f);
    }
}

extern "C" void kernel_launch(void* const* d_in, const int* in_sizes, int n_in,
                              void* d_out, int out_size, void* d_ws, size_t ws_size,
                              hipStream_t stream) {
    const float* x1 = (const float*)d_in[0];
    const float* x2 = (const float*)d_in[1];
    float* out = (float*)d_out;

    size_t need = (size_t)(X1T_ELEMS + X2T_ELEMS) * sizeof(unsigned short);
    if (ws_size >= need) {
        unsigned short* ws = (unsigned short*)d_ws;
        prep_kernel<<<B_ * H_ * 4 * 2, 256, 0, stream>>>(x1, x2, ws);
        corr_kernel<<<B_ * H_ * NOFF, 384, 0, stream>>>(ws, out);
    } else {
        corr_fallback<<<B_ * H_ * NOFF, 256, 0, stream>>>(x1, x2, out);
    }
}

// Round 3
// 178.969 us; speedup vs baseline: 1.5606x; 1.5606x over previous
//
#include <hip/hip_runtime.h>
#include <hip/hip_bf16.h>

// FlowNetC correlation: B=4, C=256, H=W=96, PAD=MAX_DISP=20, STRIDE2=2, D=21.
// out[b, oy*21+ox, h, w] = (1/C) * sum_c x1[b,c,h,w] * x2[b,c,h+2oy-20,w+2ox-20]
//
// dx even -> split w by parity. Per (b,h,oy,par): out[i,e] = sum_c A[c,i]*B[c,i+e-10]
// (i=w>>1 in [0,48), e=ox). Band GEMM, MFMA 16x16x32 bf16.
// Tiles jpad0 in {16,32,48} cover all in-range data (no pad rows stored);
// out-of-range (w2) outputs are masked at store time.
//
// corr block = (b, h, oy-half): A fragments live in registers across the oy loop;
// x2[b,h2] image (48KB) DMA'd to LDS per oy via global_load_lds (flat copy,
// wave-uniform LDS base + lane*16 HW scatter). Global layout is XOR-swizzled
// per row (chunk' = chunk ^ (row&31)) so fragment ds_read_b128 at 512B row
// stride is bank-conflict-free.

typedef __bf16 bf16x8 __attribute__((ext_vector_type(8)));
typedef float f32x4 __attribute__((ext_vector_type(4)));

#define B_ 4
#define C_ 256
#define H_ 96
#define W_ 96
#define NOFF 21
#define ROWS 96                         // rows per (b,h) image = 2 par * 48
#define IMG_ELEMS (ROWS * C_)           // 24576 ushorts = 48KB
#define X1T_ELEMS (B_ * H_ * IMG_ELEMS) // 9,437,184 ushorts

__device__ __forceinline__ unsigned short f32_to_bf16_rne(float f) {
    union { float f; unsigned u; } v; v.f = f;
    unsigned u = v.u;
    return (unsigned short)((u + 0x7fffu + ((u >> 16) & 1u)) >> 16);
}

__device__ __forceinline__ void gl2lds16(const void* g, void* l) {
    __builtin_amdgcn_global_load_lds(
        (const __attribute__((address_space(1))) void*)g,
        (__attribute__((address_space(3))) void*)l, 16, 0, 0);
}

// ---------------------------------------------------------------------------
// Prep: fp32 NCHW -> bf16 swizzled-transposed [b][h][row][chunk^(row&31)]
// row = par*48 + (w>>1), par = w&1. One block per (b,h,src,c-block-of-64).
// ---------------------------------------------------------------------------
__global__ __launch_bounds__(256) void prep_kernel(const float* __restrict__ x1,
                                                   const float* __restrict__ x2,
                                                   unsigned short* __restrict__ ws) {
    __shared__ float tile[96 * 65];   // [w][c_local], pitch 65: conflict-free
    int bid = blockIdx.x;
    int cblk  = bid & 3;
    int which = (bid >> 2) & 1;
    int bh    = bid >> 3;             // 0..383
    int h = bh % H_;
    int b = bh / H_;
    int c0 = cblk << 6;

    const float* src = (which ? x2 : x1) + ((size_t)(b * C_ + c0) * H_ + h) * W_;
    unsigned short* dst = ws + (size_t)which * X1T_ELEMS + (size_t)(b * H_ + h) * IMG_ELEMS;

    // Phase A: coalesced global reads -> LDS [w][c]
    for (int idx = threadIdx.x; idx < 64 * 96; idx += 256) {
        int c = idx / 96, w = idx - c * 96;
        tile[w * 65 + c] = src[c * (H_ * W_) + w];
    }
    __syncthreads();

    // Phase B: pack 8 c -> 16B store. Per row this c-block lands in one
    // contiguous 128B run (aligned 8-chunk group XOR'd by row bits). Dest-driven.
    for (int idx = threadIdx.x; idx < 96 * 8; idx += 256) {
        int row = idx >> 3, tp = idx & 7;
        int par = row / 48, i = row - par * 48;
        int w = 2 * i + par;
        int s = tp ^ (row & 7);                 // source chunk within c-block
        const float* fsrc = &tile[w * 65 + (s << 3)];
        unsigned pk[4];
#pragma unroll
        for (int e = 0; e < 4; ++e) {
            unsigned lo = f32_to_bf16_rne(fsrc[2 * e]);
            unsigned hi = f32_to_bf16_rne(fsrc[2 * e + 1]);
            pk[e] = lo | (hi << 16);
        }
        int ccp = (((c0 >> 3) ^ (row & 24)) + tp);   // swizzled chunk position
        *(uint4*)((char*)(dst + (size_t)row * C_) + (ccp << 4)) =
            make_uint4(pk[0], pk[1], pk[2], pk[3]);
    }
}

// ---------------------------------------------------------------------------
// Main: block = (b, h, og). 6 waves = (par, mt). oy loop over 11/10 values.
// ---------------------------------------------------------------------------
__global__ __launch_bounds__(384, 3) void corr_kernel(const unsigned short* __restrict__ ws,
                                                      float* __restrict__ out) {
    __shared__ unsigned short Bs[IMG_ELEMS];   // 48KB, swizzled flat copy of x2[b,h2]
    __shared__ float sl[NOFF][97];             // epilogue transpose slab

    int bid = blockIdx.x;
    int xcd = bid & 7, sidx = bid >> 3;        // XCD-aware: each XCD gets (b, h-half)
    int b  = xcd >> 1;
    int h  = ((xcd & 1) ? 48 : 0) + (sidx >> 1);
    int og = sidx & 1;

    int tid = threadIdx.x;
    int wv = tid >> 6, lane = tid & 63;
    int par = wv & 1, mt = wv >> 1;
    int i0 = mt << 4;
    int n = lane & 15, quad = lane >> 4;

    // A fragments: loaded once from global, reused for all oy.
    int rowA = par * 48 + i0 + n;
    const unsigned short* Ag = ws + (size_t)(b * H_ + h) * IMG_ELEMS + (size_t)rowA * C_;
    int keyA = rowA & 31;
    bf16x8 afrag[8];
#pragma unroll
    for (int ks = 0; ks < 8; ++ks)
        afrag[ks] = *(const bf16x8*)(Ag + ((((ks << 2) | quad) ^ keyA) << 3));

    const unsigned short* Bimg = ws + (size_t)X1T_ELEMS + (size_t)(b * H_) * IMG_ELEMS;

    int rowB0 = par * 48 + n;          // u=0 (j 0..15)
    int rowB1 = rowB0 + 16;            // u=1 (j 16..31)
    int rowB2 = rowB0 + 32;            // u=2 (j 32..47)
    int keyB0 = rowB0 & 31, keyB1 = rowB1 & 31, keyB2 = rowB2 & 31;

    int oy_lo = og ? 11 : 0;
    int oy_hi = og ? NOFF : 11;
    int wvoff  = wv * 8192;            // wave-uniform LDS base offset
    int gmaoff = wvoff + lane * 16;    // per-lane global offset

    for (int oy = oy_lo; oy < oy_hi; ++oy) {
        int h2 = h + 2 * oy - 20;
        int outb = ((b * 441 + oy * NOFF) * H_ + h) * W_;
        if (h2 < 0 || h2 >= H_) {
            for (int idx = tid; idx < NOFF * W_; idx += 384)
                out[outb + (idx / W_) * (H_ * W_) + (idx % W_)] = 0.0f;
            continue;
        }

        // DMA x2[b,h2] image -> LDS (flat copy preserves swizzle). 8 x 16B/thread.
        // LDS base is wave-uniform; HW scatters lane i at base + i*16.
        const char* Bg = (const char*)(Bimg + (size_t)h2 * IMG_ELEMS);
#pragma unroll
        for (int c = 0; c < 8; ++c)
            gl2lds16(Bg + gmaoff + c * 1024, (char*)Bs + wvoff + c * 1024);
        __syncthreads();   // drains DMA (vmcnt 0) + barrier

        f32x4 acc0 = {0.f,0.f,0.f,0.f}, acc1 = {0.f,0.f,0.f,0.f}, acc2 = {0.f,0.f,0.f,0.f};
        const char* Bsb = (const char*)Bs;
        // valid B tiles per M-tile: mt0:{u0,u1} mt1:{u0,u1,u2} mt2:{u1,u2}
        if (mt == 0) {
#pragma unroll
            for (int ks = 0; ks < 8; ++ks) {
                int ci = (ks << 2) | quad;
                bf16x8 b0 = *(const bf16x8*)(Bsb + rowB0 * 512 + ((ci ^ keyB0) << 4));
                bf16x8 b1 = *(const bf16x8*)(Bsb + rowB1 * 512 + ((ci ^ keyB1) << 4));
                acc0 = __builtin_amdgcn_mfma_f32_16x16x32_bf16(afrag[ks], b0, acc0, 0, 0, 0);
                acc1 = __builtin_amdgcn_mfma_f32_16x16x32_bf16(afrag[ks], b1, acc1, 0, 0, 0);
            }
        } else if (mt == 1) {
#pragma unroll
            for (int ks = 0; ks < 8; ++ks) {
                int ci = (ks << 2) | quad;
                bf16x8 b0 = *(const bf16x8*)(Bsb + rowB0 * 512 + ((ci ^ keyB0) << 4));
                bf16x8 b1 = *(const bf16x8*)(Bsb + rowB1 * 512 + ((ci ^ keyB1) << 4));
                bf16x8 b2 = *(const bf16x8*)(Bsb + rowB2 * 512 + ((ci ^ keyB2) << 4));
                acc0 = __builtin_amdgcn_mfma_f32_16x16x32_bf16(afrag[ks], b0, acc0, 0, 0, 0);
                acc1 = __builtin_amdgcn_mfma_f32_16x16x32_bf16(afrag[ks], b1, acc1, 0, 0, 0);
                acc2 = __builtin_amdgcn_mfma_f32_16x16x32_bf16(afrag[ks], b2, acc2, 0, 0, 0);
            }
        } else {
#pragma unroll
            for (int ks = 0; ks < 8; ++ks) {
                int ci = (ks << 2) | quad;
                bf16x8 b1 = *(const bf16x8*)(Bsb + rowB1 * 512 + ((ci ^ keyB1) << 4));
                bf16x8 b2 = *(const bf16x8*)(Bsb + rowB2 * 512 + ((ci ^ keyB2) << 4));
                acc1 = __builtin_amdgcn_mfma_f32_16x16x32_bf16(afrag[ks], b1, acc1, 0, 0, 0);
                acc2 = __builtin_amdgcn_mfma_f32_16x16x32_bf16(afrag[ks], b2, acc2, 0, 0, 0);
            }
        }

        // Scatter valid band entries. C/D: col n = lane&15, row m = quad*4+r.
        // ox = 16*(u+1) + n - (i0+m) - 6.
#pragma unroll
        for (int r = 0; r < 4; ++r) {
            int m = (quad << 2) + r;
            int w = 2 * (i0 + m) + par;
            int oxb = n - i0 - m - 6;
            if (mt != 2) { int ox = 16 + oxb; if (ox >= 0 && ox < NOFF) sl[ox][w] = acc0[r]; }
            {             int ox = 32 + oxb; if (ox >= 0 && ox < NOFF) sl[ox][w] = acc1[r]; }
            if (mt != 0) { int ox = 48 + oxb; if (ox >= 0 && ox < NOFF) sl[ox][w] = acc2[r]; }
        }
        __syncthreads();

        // Store: stale slab entries are exactly the out-of-range (masked) ones.
        for (int idx = tid; idx < NOFF * W_; idx += 384) {
            int ox = idx / W_, w = idx - ox * W_;
            int w2 = w + 2 * ox - 20;
            float v = (w2 >= 0 && w2 < W_) ? sl[ox][w] * (1.0f / 256.0f) : 0.0f;
            out[outb + ox * (H_ * W_) + w] = v;
        }
    }
}

// ---------------------------------------------------------------------------
// Fallback (ws too small): direct fp32, slow but correct.
// ---------------------------------------------------------------------------
__global__ __launch_bounds__(256) void corr_fallback(const float* __restrict__ x1,
                                                     const float* __restrict__ x2,
                                                     float* __restrict__ out) {
    int bid = blockIdx.x;
    int oy = bid % NOFF, h = (bid / NOFF) % H_, b = bid / (NOFF * H_);
    int dy = 2 * oy - 20, h2 = h + dy;
    int outbase = ((b * 441 + oy * NOFF) * H_ + h) * W_;
    for (int idx = threadIdx.x; idx < NOFF * W_; idx += 256) {
        int ox = idx / W_, w = idx % W_;
        float acc = 0.f;
        int w2 = w + 2 * ox - 20;
        if (h2 >= 0 && h2 < H_ && w2 >= 0 && w2 < W_) {
            const float* p1 = x1 + (size_t)b * C_ * H_ * W_ + h * W_ + w;
            const float* p2 = x2 + (size_t)b * C_ * H_ * W_ + h2 * W_ + w2;
            for (int c = 0; c < C_; ++c) acc += p1[c * (H_ * W_)] * p2[c * (H_ * W_)];
        }
        out[outbase + ox * (H_ * W_) + w] = acc * (1.0f / 256.0f);
    }
}

extern "C" void kernel_launch(void* const* d_in, const int* in_sizes, int n_in,
                              void* d_out, int out_size, void* d_ws, size_t ws_size,
                              hipStream_t stream) {
    const float* x1 = (const float*)d_in[0];
    const float* x2 = (const float*)d_in[1];
    float* out = (float*)d_out;

    size_t need = (size_t)2 * X1T_ELEMS * sizeof(unsigned short);  // 37.7 MB
    if (ws_size >= need) {
        unsigned short* ws = (unsigned short*)d_ws;
        prep_kernel<<<B_ * H_ * 2 * 4, 256, 0, stream>>>(x1, x2, ws);
        corr_kernel<<<768, 384, 0, stream>>>(ws, out);
    } else {
        corr_fallback<<<B_ * H_ * NOFF, 256, 0, stream>>>(x1, x2, out);
    }
}